// Round 15
// baseline (102.553 us; speedup 1.0000x reference)
//
#include <hip/hip_runtime.h>

#define NIMG 192
#define NPIX (256*256)
#define N_TOTAL (192*65536)
typedef unsigned long long u64;

__device__ __forceinline__ int refl(int i){ i = i < 0 ? -i : i; return i > 255 ? 510 - i : i; }

// DPP wave-wide lane shifts. shr1: lane n <- n-1 (lane0 -> oldv). shl1: lane n <- n+1
// (lane63 -> oldv). *z: invalid lane -> 0.
__device__ __forceinline__ float dpp_shr1(float src, float oldv) {
    return __int_as_float(__builtin_amdgcn_update_dpp(
        __float_as_int(oldv), __float_as_int(src), 0x138, 0xF, 0xF, false));
}
__device__ __forceinline__ float dpp_shl1(float src, float oldv) {
    return __int_as_float(__builtin_amdgcn_update_dpp(
        __float_as_int(oldv), __float_as_int(src), 0x130, 0xF, 0xF, false));
}
__device__ __forceinline__ float dpp_shr1z(float src) {
    return __int_as_float(__builtin_amdgcn_update_dpp(
        0, __float_as_int(src), 0x138, 0xF, 0xF, true));
}
__device__ __forceinline__ float dpp_shl1z(float src) {
    return __int_as_float(__builtin_amdgcn_update_dpp(
        0, __float_as_int(src), 0x130, 0xF, 0xF, true));
}

// Per-image pipeline state: NAMED members only, two distinct locals (A, B) —
// no runtime-indexed arrays (r12 spill lesson / rule #20).
struct ImgS {
    float hwB[4], hwC[4], hwD[4], hwE[4], boP[4], boQ[4];
    float mgA[4], mgB[4], mgAL, mgAR, mgBL, mgBR;
    float gxp[4], gyp[4];
    float4 cur;
    const float4* pi;
    u64* mo;
    const float* img;
    u64* mk;
};

// ---------------- Kernel 1: pair-merged rolling canny front-end ----------------
// One wave per (PAIR, 16-row band): pred AND batch rows each step — two independent
// dep chains (1.5x per-wave issue rate, measured r13). (256,3): VGPR cap 168,
// kernel needs ~96 -> no spill AND 3 waves/SIMD (r13's (256,2) left only 2).
// Mask row r = 8 u64 [w0..w3, s0..s3] at masks + iy*2048 + r*8; word j bit l = col 4l+j.
__global__ __launch_bounds__(256, 3) void k_edges(
    const float* __restrict__ pred, const float* __restrict__ batch,
    u64* __restrict__ masks, double* __restrict__ sse)
{
    const int wv = threadIdx.x >> 6, lane = threadIdx.x & 63;
    const int band = blockIdx.x * 4 + wv;            // 0..15
    const int pair = blockIdx.y;                     // 0..191
    const int R0 = band * 16, R1 = R0 + 15;

    const float W0 = 0.0544886850f, W1 = 0.2442013420f, W2 = 0.4026199469f;
    const float LO2 = 0.01f, HI2 = 0.04f, T1 = 0.41421356237f;

    ImgS A, B;
    A.img = pred  + (size_t)pair * NPIX;
    B.img = batch + (size_t)pair * NPIX;
    A.mk = masks + (size_t)pair * 2048;
    B.mk = masks + (size_t)(pair + NIMG) * 2048;
    float acc = 0.f;

    auto HB = [&](const float4& c, float hb[4]) {
        float Lz = dpp_shr1(c.z, c.z), Lw = dpp_shr1(c.w, c.y);
        float Rx = dpp_shl1(c.x, c.z), Ry = dpp_shl1(c.y, c.y);
        hb[0] = W0*(Lz + c.z) + W1*(Lw + c.y)  + W2*c.x;
        hb[1] = W0*(Lw + c.w) + W1*(c.x + c.z) + W2*c.y;
        hb[2] = W0*(c.x + Rx) + W1*(c.y + c.w) + W2*c.z;
        hb[3] = W0*(c.y + Ry) + W1*(c.z + Rx)  + W2*c.w;
    };
    auto VB = [&](const float a[4], const float b_[4], const float c[4],
                  const float d[4], const float e[4], float o[4]) {
        #pragma unroll
        for (int k = 0; k < 4; ++k) o[k] = W0*(a[k]+e[k]) + W1*(b_[k]+d[k]) + W2*c[k];
    };
    auto SOB = [&](const float lo[4], const float mid[4], const float hi[4],
                   float gx[4], float gy[4], float mg[4], float& SL, float& SR) {
        float t[4], u[4];
        #pragma unroll
        for (int k = 0; k < 4; ++k) { t[k] = lo[k] + 2.f*mid[k] + hi[k]; u[k] = hi[k] - lo[k]; }
        float Lt = dpp_shr1(t[3], t[0]), Rt = dpp_shl1(t[0], t[3]);
        float Lu = dpp_shr1(u[3], u[0]), Ru = dpp_shl1(u[0], u[3]);
        gx[0] = t[1] - Lt; gx[1] = t[2] - t[0]; gx[2] = t[3] - t[1]; gx[3] = Rt - t[2];
        gy[0] = (Lu + u[1]) + 2.f*u[0];  gy[1] = (u[0] + u[2]) + 2.f*u[1];
        gy[2] = (u[1] + u[3]) + 2.f*u[2]; gy[3] = (u[2] + Ru) + 2.f*u[3];
        #pragma unroll
        for (int k = 0; k < 4; ++k) mg[k] = fmaf(gx[k], gx[k], fmaf(gy[k], gy[k], 1e-6f));
        SL = dpp_shr1z(mg[3]); SR = dpp_shl1z(mg[0]);
    };
    auto MSE4 = [&](const float4& a, const float4& o) {
        float dx = a.x - o.x, dy = a.y - o.y, dz = a.z - o.z, dw = a.w - o.w;
        acc += dx*dx + dy*dy + dz*dz + dw*dw;
    };

    auto donms = [&](ImgS& s, const float mgC[4], const float CL, const float CR,
                     u64* dst) {
        u64 wB[4], sB[4];
        #pragma unroll
        for (int k = 0; k < 4; ++k) {
            const float gxv = s.gxp[k], gyv = s.gyp[k];
            const float ax = fabsf(gxv), ay = fabsf(gyv);
            const bool horiz = (ay <= T1 * ax);
            const bool vert  = (ax <= T1 * ay);
            const bool d45 = (int)(__float_as_uint(gxv) ^ __float_as_uint(gyv)) >= 0;
            const float Ap = (k < 3) ? s.mgA[k+1] : s.mgAR;
            const float Am = (k > 0) ? s.mgA[k-1] : s.mgAL;
            const float Bp = (k < 3) ? s.mgB[k+1] : s.mgBR;
            const float Bm = (k > 0) ? s.mgB[k-1] : s.mgBL;
            const float Cp = (k < 3) ? mgC[k+1] : CR;
            const float Cm = (k > 0) ? mgC[k-1] : CL;
            const float m1 = horiz ? Bp : (vert ? mgC[k]   : (d45 ? Ap : Cp));
            const float m2 = horiz ? Bm : (vert ? s.mgA[k] : (d45 ? Cm : Am));
            const float M  = fmaxf(fmaxf(m1, m2), LO2);
            const float v  = s.mgB[k];
            wB[k] = __ballot(v > M);
            sB[k] = __ballot(v > fmaxf(M, HI2));
        }
        if (lane == 0) {
            ulonglong2 q;
            q.x = wB[0]; q.y = wB[1]; ((ulonglong2*)dst)[0] = q;
            q.x = wB[2]; q.y = wB[3]; ((ulonglong2*)dst)[1] = q;
            q.x = sB[0]; q.y = sB[1]; ((ulonglong2*)dst)[2] = q;
            q.x = sB[2]; q.y = sB[3]; ((ulonglong2*)dst)[3] = q;
        }
    };

    auto rotate = [&](ImgS& s, const float hb[4], const float blv[4], const float mgC[4],
                      const float CL, const float CR, const float gx[4], const float gy[4]) {
        #pragma unroll
        for (int k = 0; k < 4; ++k) {
            s.hwB[k]=s.hwC[k]; s.hwC[k]=s.hwD[k]; s.hwD[k]=s.hwE[k]; s.hwE[k]=hb[k];
            s.boP[k]=s.boQ[k]; s.boQ[k]=blv[k];
            s.mgA[k]=s.mgB[k]; s.mgB[k]=mgC[k];
            s.gxp[k]=gx[k];    s.gyp[k]=gy[k];
        }
        s.mgAL=s.mgBL; s.mgBL=CL; s.mgAR=s.mgBR; s.mgBR=CR;
    };

    // fast (branch-free) per-image body: NMS row b-2 -> *s.mo
    auto fbody = [&](ImgS& s) {
        float hb[4];
        HB(s.cur, hb);
        float blv[4];
        #pragma unroll
        for (int k = 0; k < 4; ++k)
            blv[k] = W0*(s.hwB[k] + hb[k]) + W1*(s.hwC[k] + s.hwE[k]) + W2*s.hwD[k];
        float gx[4], gy[4], mgC[4], CL, CR;
        SOB(s.boP, s.boQ, blv, gx, gy, mgC, CL, CR);
        donms(s, mgC, CL, CR, s.mo); s.mo += 8;
        rotate(s, hb, blv, mgC, CL, CR, gx, gy);
    };

    // generic (boundary) per-image body: guards for m==0/255, row range
    auto sbody = [&](ImgS& s, const int b) {
        const int m = b - 1, r = b - 2;
        float hb[4];
        HB(s.cur, hb);
        float t[4], u[4], blv[4];
        #pragma unroll
        for (int k = 0; k < 4; ++k) {
            blv[k] = W0*(s.hwB[k] + hb[k]) + W1*(s.hwC[k] + s.hwE[k]) + W2*s.hwD[k];
            float lo = (m == 0)   ? s.boQ[k] : s.boP[k];
            float hi = (m == 255) ? s.boQ[k] : blv[k];
            t[k] = lo + 2.f*s.boQ[k] + hi;
            u[k] = hi - lo;
        }
        float Lt = dpp_shr1(t[3], t[0]), Rt = dpp_shl1(t[0], t[3]);
        float Lu = dpp_shr1(u[3], u[0]), Ru = dpp_shl1(u[0], u[3]);
        float gx[4], gy[4], mgC[4];
        gx[0] = t[1] - Lt; gx[1] = t[2] - t[0]; gx[2] = t[3] - t[1]; gx[3] = Rt - t[2];
        gy[0] = (Lu + u[1]) + 2.f*u[0];  gy[1] = (u[0] + u[2]) + 2.f*u[1];
        gy[2] = (u[1] + u[3]) + 2.f*u[2]; gy[3] = (u[2] + Ru) + 2.f*u[3];
        #pragma unroll
        for (int k = 0; k < 4; ++k) mgC[k] = fmaf(gx[k], gx[k], fmaf(gy[k], gy[k], 1e-6f));
        if (m < 0 || m > 255) { mgC[0]=mgC[1]=mgC[2]=mgC[3]=0.f; }
        float CL = dpp_shr1z(mgC[3]), CR = dpp_shl1z(mgC[0]);
        if (r >= R0 && r <= R1) donms(s, mgC, CL, CR, s.mk + r * 8);
        rotate(s, hb, blv, mgC, CL, CR, gx, gy);
    };

    const int glo = (band == 0) ? 0 : 252;           // generic-step MSE rows glo..glo+3
    auto steprow = [&](const int b) {
        float4 nA = *(const float4*)(A.img + (size_t)refl(b + 3) * 256 + (lane << 2));
        float4 nB = *(const float4*)(B.img + (size_t)refl(b + 3) * 256 + (lane << 2));
        sbody(A, b);
        sbody(B, b);
        if ((unsigned)(b + 2 - glo) <= 3u) MSE4(A.cur, B.cur);
        A.cur = nA; B.cur = nB;
    };
    auto fastrow = [&](const int b) {
        float4 nA = *A.pi; A.pi += 64;
        float4 nB = *B.pi; B.pi += 64;
        fbody(A);
        fbody(B);
        if (b <= R1 - 2) MSE4(A.cur, B.cur);         // rows R0+4..R1
        A.cur = nA; B.cur = nB;
    };

    // straight-line minimal warm-up (rows R0-4..R0+4, no guards; bands 1-15)
    auto warmup = [&](ImgS& s) {
        auto ldr = [&](int r){ return *((const float4*)(s.img + (size_t)r * 256) + lane); };
        float4 c0 = ldr(R0 - 4), c1 = ldr(R0 - 3);
        float h0[4],h1[4],h2[4],h3[4],h4[4],h5[4],h6[4],h7[4];
        float bo0[4],bo1[4],bo2[4],bo3[4];
        HB(c0, h0); c0 = ldr(R0 - 2);
        HB(c1, h1); c1 = ldr(R0 - 1);
        HB(c0, h2); c0 = ldr(R0);
        HB(c1, h3); c1 = ldr(R0 + 1);
        HB(c0, h4); c0 = ldr(R0 + 2);
        HB(c1, h5); c1 = ldr(R0 + 3);
        VB(h0, h1, h2, h3, h4, bo0);                 // blv row R0-2
        VB(h1, h2, h3, h4, h5, bo1);                 // blv row R0-1
        HB(c0, h6); c0 = ldr(R0 + 4);
        VB(h2, h3, h4, h5, h6, bo2);                 // blv row R0
        { float dgx[4], dgy[4]; SOB(bo0, bo1, bo2, dgx, dgy, s.mgA, s.mgAL, s.mgAR); }
        HB(c1, h7);
        VB(h3, h4, h5, h6, h7, bo3);                 // blv row R0+1
        SOB(bo1, bo2, bo3, s.gxp, s.gyp, s.mgB, s.mgBL, s.mgBR);   // sobel/mag row R0
        #pragma unroll
        for (int k = 0; k < 4; ++k) {
            s.hwB[k]=h4[k]; s.hwC[k]=h5[k]; s.hwD[k]=h6[k]; s.hwE[k]=h7[k];
            s.boP[k]=bo2[k]; s.boQ[k]=bo3[k];
        }
        s.cur = c0;                                  // row R0+4
        s.pi = (const float4*)s.img + ((size_t)(R0 + 5) << 6) + lane;
    };

    int b;
    if (band == 0) {
        // generic prologue: reflect rows + m==0 guard; MSE rows 0..3 via gate.
        #pragma unroll
        for (int k = 0; k < 4; ++k) {
            A.hwB[k]=A.hwC[k]=A.hwD[k]=A.hwE[k]=0.f; A.boP[k]=A.boQ[k]=0.f;
            A.mgA[k]=A.mgB[k]=0.f; A.gxp[k]=A.gyp[k]=0.f;
            B.hwB[k]=B.hwC[k]=B.hwD[k]=B.hwE[k]=0.f; B.boP[k]=B.boQ[k]=0.f;
            B.mgA[k]=B.mgB[k]=0.f; B.gxp[k]=B.gyp[k]=0.f;
        }
        A.mgAL=A.mgAR=A.mgBL=A.mgBR=0.f;
        B.mgAL=B.mgAR=B.mgBL=B.mgBR=0.f;
        A.cur = *(const float4*)(A.img + (size_t)refl(-4) * 256 + (lane << 2));
        B.cur = *(const float4*)(B.img + (size_t)refl(-4) * 256 + (lane << 2));
        for (b = -6; b <= 1; ++b) steprow(b);        // ends: cur = row 4, b = 2
        A.pi = (const float4*)A.img + ((size_t)5 << 6) + lane;
        B.pi = (const float4*)B.img + ((size_t)5 << 6) + lane;
    } else {
        warmup(A);
        warmup(B);
        // MSE rows R0..R0+3 (hot reload from L2)
        #pragma unroll
        for (int rr = 0; rr < 4; ++rr) {
            float4 a = *((const float4*)(A.img + (size_t)(R0 + rr) * 256) + lane);
            float4 o = *((const float4*)(B.img + (size_t)(R0 + rr) * 256) + lane);
            MSE4(a, o);
        }
        b = R0 + 2;
    }
    A.mo = A.mk + (size_t)R0 * 8;
    B.mo = B.mk + (size_t)R0 * 8;

    const int nfast = (band == 15) ? 8 : 16;         // NMS rows R0.. via fast path
    for (int i = 0; i < nfast; ++i) { fastrow(b); ++b; }
    if (band == 15) {
        for (; b <= 257; ++b) steprow(b);            // rows 248..255: m==255 + refl tail
    }

    for (int off = 32; off; off >>= 1) acc += __shfl_down(acc, off);
    if (lane == 0)
        atomicAdd(&sse[(blockIdx.y * 4 + blockIdx.x) & 63], (double)acc);
}

// ------- Kernel 2: per-pair hysteresis fixpoint + inline strong-diff count ----------
// Row layout: 8 u64 per row = [w0..w3, s0..s3]. Bit: word j bit l = col 4l+j.
__global__ __launch_bounds__(256) void k_hyst(const u64* __restrict__ masks,
                                              u64* __restrict__ cnt)
{
    const int pr = blockIdx.x;                       // pair 0..191
    const u64* rp = masks + (size_t)pr * 2048 + (size_t)threadIdx.x * 8;
    const u64* rt = masks + (size_t)(pr + NIMG) * 2048 + (size_t)threadIdx.x * 8;
    const int r = threadIdx.x;                       // row 0..255
    __shared__ u64 hd[8][256];
    __shared__ int flg[2];
    __shared__ int wsum[4];
    ulonglong2 a0 = ((const ulonglong2*)rp)[0];
    ulonglong2 a1 = ((const ulonglong2*)rp)[1];
    ulonglong2 a2 = ((const ulonglong2*)rp)[2];
    ulonglong2 a3 = ((const ulonglong2*)rp)[3];
    ulonglong2 b0 = ((const ulonglong2*)rt)[0];
    ulonglong2 b1 = ((const ulonglong2*)rt)[1];
    ulonglong2 b2 = ((const ulonglong2*)rt)[2];
    ulonglong2 b3 = ((const ulonglong2*)rt)[3];
    u64 pw0=a0.x, pw1=a0.y, pw2=a1.x, pw3=a1.y;
    u64 ps0=a2.x, ps1=a2.y, ps2=a3.x, ps3=a3.y;
    u64 tw0=b0.x, tw1=b0.y, tw2=b1.x, tw3=b1.y;
    u64 ts0=b2.x, ts1=b2.y, ts2=b3.x, ts3=b3.y;
    if (r < 2) flg[r] = 0;
    const int up = r ? r - 1 : 0, dn = (r < 255) ? r + 1 : 255;
    for (int k = 0;; ++k) {
        u64 hp0 = ps0 | (ps3 << 1) | ps1;
        u64 hp1 = ps1 | ps0 | ps2;
        u64 hp2 = ps2 | ps1 | ps3;
        u64 hp3 = ps3 | ps2 | (ps0 >> 1);
        u64 ht0 = ts0 | (ts3 << 1) | ts1;
        u64 ht1 = ts1 | ts0 | ts2;
        u64 ht2 = ts2 | ts1 | ts3;
        u64 ht3 = ts3 | ts2 | (ts0 >> 1);
        hd[0][r]=hp0; hd[1][r]=hp1; hd[2][r]=hp2; hd[3][r]=hp3;
        hd[4][r]=ht0; hd[5][r]=ht1; hd[6][r]=ht2; hd[7][r]=ht3;
        if (r == 0) flg[(k + 1) & 1] = 0;
        __syncthreads();
        u64 n0 = ps0 | ((hp0 | hd[0][up] | hd[0][dn]) & pw0);
        u64 n1 = ps1 | ((hp1 | hd[1][up] | hd[1][dn]) & pw1);
        u64 n2 = ps2 | ((hp2 | hd[2][up] | hd[2][dn]) & pw2);
        u64 n3 = ps3 | ((hp3 | hd[3][up] | hd[3][dn]) & pw3);
        u64 m0 = ts0 | ((ht0 | hd[4][up] | hd[4][dn]) & tw0);
        u64 m1 = ts1 | ((ht1 | hd[5][up] | hd[5][dn]) & tw1);
        u64 m2 = ts2 | ((ht2 | hd[6][up] | hd[6][dn]) & tw2);
        u64 m3 = ts3 | ((ht3 | hd[7][up] | hd[7][dn]) & tw3);
        u64 chg = (n0^ps0)|(n1^ps1)|(n2^ps2)|(n3^ps3)|(m0^ts0)|(m1^ts1)|(m2^ts2)|(m3^ts3);
        ps0=n0; ps1=n1; ps2=n2; ps3=n3; ts0=m0; ts1=m1; ts2=m2; ts3=m3;
        if (chg) flg[k & 1] = 1;
        __syncthreads();
        if (!flg[k & 1]) break;
    }
    int c = __popcll(ps0^ts0) + __popcll(ps1^ts1) + __popcll(ps2^ts2) + __popcll(ps3^ts3);
    for (int off = 32; off; off >>= 1) c += __shfl_down(c, off);
    if ((threadIdx.x & 63) == 0) wsum[threadIdx.x >> 6] = c;
    __syncthreads();
    if (threadIdx.x == 0)
        atomicAdd(cnt, (u64)(wsum[0] + wsum[1] + wsum[2] + wsum[3]));
}

// ---------------- Kernel 3: combine --------------------------------------------------
__global__ void k_final(const double* __restrict__ sse, const u64* __restrict__ cnt,
                        float* __restrict__ out)
{
    double s = 0.0;
    for (int i = 0; i < 64; ++i) s += sse[i];
    float mse1 = (float)(s / (double)N_TOTAL);
    float mse2 = (float)((double)(*cnt) / (double)N_TOTAL);
    out[0] = 0.85f * mse1 + (1.0f - 0.85f) * mse2;
}

extern "C" void kernel_launch(void* const* d_in, const int* in_sizes, int n_in,
                              void* d_out, int out_size, void* d_ws, size_t ws_size,
                              hipStream_t stream)
{
    const float* pred  = (const float*)d_in[0];
    const float* batch = (const float*)d_in[1];
    float* out = (float*)d_out;
    double* sse = (double*)d_ws;                       // 64 doubles
    u64* cnt    = (u64*)((char*)d_ws + 512);
    u64* masks  = (u64*)((char*)d_ws + 1024);          // 384 * 2048 u64

    hipMemsetAsync(d_ws, 0, 1024, stream);
    dim3 g1(4, 192);                                   // 16 bands x 192 pairs
    k_edges<<<g1, 256, 0, stream>>>(pred, batch, masks, sse);
    k_hyst<<<192, 256, 0, stream>>>(masks, cnt);
    k_final<<<1, 1, 0, stream>>>(sse, cnt, out);
}

// Round 16
// 62.047 us; speedup vs baseline: 1.6528x; 1.6528x over previous
//
#include <hip/hip_runtime.h>

#define NIMG 192
#define NPIX (256*256)
#define N_TOTAL (192*65536)
typedef unsigned long long u64;

__device__ __forceinline__ int refl(int i){ i = i < 0 ? -i : i; return i > 255 ? 510 - i : i; }

// DPP wave-wide lane shifts. shr1: lane n <- n-1 (lane0 -> oldv). shl1: lane n <- n+1
// (lane63 -> oldv). *z: invalid lane -> 0.
__device__ __forceinline__ float dpp_shr1(float src, float oldv) {
    return __int_as_float(__builtin_amdgcn_update_dpp(
        __float_as_int(oldv), __float_as_int(src), 0x138, 0xF, 0xF, false));
}
__device__ __forceinline__ float dpp_shl1(float src, float oldv) {
    return __int_as_float(__builtin_amdgcn_update_dpp(
        __float_as_int(oldv), __float_as_int(src), 0x130, 0xF, 0xF, false));
}
__device__ __forceinline__ float dpp_shr1z(float src) {
    return __int_as_float(__builtin_amdgcn_update_dpp(
        0, __float_as_int(src), 0x138, 0xF, 0xF, true));
}
__device__ __forceinline__ float dpp_shl1z(float src) {
    return __int_as_float(__builtin_amdgcn_update_dpp(
        0, __float_as_int(src), 0x130, 0xF, 0xF, true));
}

// ---------------- Kernel 1: all-register rolling canny front-end ----------------
// BEST MEASURED CONFIG (r11, 63.1 us total): one wave per (image, 32-row band);
// 768 blocks, 3 waves/SIMD, 60 VGPR, no spill. 2-deep prefetch on both streams.
// Mask row r = 8 u64 [w0..w3, s0..s3] at masks + iy*2048 + r*8; word j bit l = col 4l+j.
__global__ __launch_bounds__(256, 3) void k_edges(
    const float* __restrict__ pred, const float* __restrict__ batch,
    u64* __restrict__ masks, double* __restrict__ sse)
{
    const int wv = threadIdx.x >> 6, lane = threadIdx.x & 63;
    const int band = blockIdx.x * 4 + wv;            // 0..7
    const int iy   = blockIdx.y;                     // 0..383
    const int R0 = band * 32, R1 = R0 + 31;
    const bool isPred = iy < NIMG;
    const float* img  = isPred ? pred  + (size_t)iy * NPIX : batch + (size_t)(iy - NIMG) * NPIX;
    const float* oimg = isPred ? batch + (size_t)iy * NPIX : pred  + (size_t)(iy - NIMG) * NPIX;
    u64* mout = masks + (size_t)iy * 2048;
    const int mlo  = isPred ? R0 : R0 + 16;          // generic-step MSE window base
    const int mloF = isPred ? R0 + 4 : R0 + 16;      // fastrow MSE window
    const unsigned spanF = isPred ? 11u : 15u;

    const float W0 = 0.0544886850f, W1 = 0.2442013420f, W2 = 0.4026199469f;
    const float LO2 = 0.01f, HI2 = 0.04f, T1 = 0.41421356237f;

    float hwB[4], hwC[4], hwD[4], hwE[4], boP[4], boQ[4];
    float mgA[4], mgB[4], mgAL, mgAR, mgBL, mgBR, gxp[4], gyp[4];
    float4 cur, nx1, oc, oc1;
    float acc = 0.f;
    const float4 *pi = nullptr, *po = nullptr;
    u64* mo = nullptr;

    auto HB = [&](const float4& c, float hb[4]) {
        float Lz = dpp_shr1(c.z, c.z), Lw = dpp_shr1(c.w, c.y);
        float Rx = dpp_shl1(c.x, c.z), Ry = dpp_shl1(c.y, c.y);
        hb[0] = W0*(Lz + c.z) + W1*(Lw + c.y)  + W2*c.x;
        hb[1] = W0*(Lw + c.w) + W1*(c.x + c.z) + W2*c.y;
        hb[2] = W0*(c.x + Rx) + W1*(c.y + c.w) + W2*c.z;
        hb[3] = W0*(c.y + Ry) + W1*(c.z + Rx)  + W2*c.w;
    };
    auto VB = [&](const float a[4], const float b_[4], const float c[4],
                  const float d[4], const float e[4], float o[4]) {
        #pragma unroll
        for (int k = 0; k < 4; ++k) o[k] = W0*(a[k]+e[k]) + W1*(b_[k]+d[k]) + W2*c[k];
    };
    auto SOB = [&](const float lo[4], const float mid[4], const float hi[4],
                   float gx[4], float gy[4], float mg[4], float& SL, float& SR) {
        float t[4], u[4];
        #pragma unroll
        for (int k = 0; k < 4; ++k) { t[k] = lo[k] + 2.f*mid[k] + hi[k]; u[k] = hi[k] - lo[k]; }
        float Lt = dpp_shr1(t[3], t[0]), Rt = dpp_shl1(t[0], t[3]);
        float Lu = dpp_shr1(u[3], u[0]), Ru = dpp_shl1(u[0], u[3]);
        gx[0] = t[1] - Lt; gx[1] = t[2] - t[0]; gx[2] = t[3] - t[1]; gx[3] = Rt - t[2];
        gy[0] = (Lu + u[1]) + 2.f*u[0];  gy[1] = (u[0] + u[2]) + 2.f*u[1];
        gy[2] = (u[1] + u[3]) + 2.f*u[2]; gy[3] = (u[2] + Ru) + 2.f*u[3];
        #pragma unroll
        for (int k = 0; k < 4; ++k) mg[k] = fmaf(gx[k], gx[k], fmaf(gy[k], gy[k], 1e-6f));
        SL = dpp_shr1z(mg[3]); SR = dpp_shl1z(mg[0]);
    };
    auto MSE4 = [&](const float4& a, const float4& o) {
        float dx = a.x - o.x, dy = a.y - o.y, dz = a.z - o.z, dw = a.w - o.w;
        acc += dx*dx + dy*dy + dz*dz + dw*dw;
    };

    auto donms = [&](const float mgC[4], const float CL, const float CR, u64* dst) {
        u64 wB[4], sB[4];
        #pragma unroll
        for (int k = 0; k < 4; ++k) {
            const float gxv = gxp[k], gyv = gyp[k];
            const float ax = fabsf(gxv), ay = fabsf(gyv);
            const bool horiz = (ay <= T1 * ax);
            const bool vert  = (ax <= T1 * ay);
            const bool d45 = (int)(__float_as_uint(gxv) ^ __float_as_uint(gyv)) >= 0;
            const float Ap = (k < 3) ? mgA[k+1] : mgAR, Am = (k > 0) ? mgA[k-1] : mgAL;
            const float Bp = (k < 3) ? mgB[k+1] : mgBR, Bm = (k > 0) ? mgB[k-1] : mgBL;
            const float Cp = (k < 3) ? mgC[k+1] : CR,   Cm = (k > 0) ? mgC[k-1] : CL;
            const float m1 = horiz ? Bp : (vert ? mgC[k] : (d45 ? Ap : Cp));
            const float m2 = horiz ? Bm : (vert ? mgA[k] : (d45 ? Cm : Am));
            const float M  = fmaxf(fmaxf(m1, m2), LO2);
            const float v  = mgB[k];
            wB[k] = __ballot(v > M);
            sB[k] = __ballot(v > fmaxf(M, HI2));
        }
        if (lane == 0) {
            ulonglong2 q;
            q.x = wB[0]; q.y = wB[1]; ((ulonglong2*)dst)[0] = q;
            q.x = wB[2]; q.y = wB[3]; ((ulonglong2*)dst)[1] = q;
            q.x = sB[0]; q.y = sB[1]; ((ulonglong2*)dst)[2] = q;
            q.x = sB[2]; q.y = sB[3]; ((ulonglong2*)dst)[3] = q;
        }
    };

    // generic (boundary) row step — band 0 prologue & band 7 tail only (1-deep)
    auto steprow = [&](const int b) {
        float4 nxt = *(const float4*)(img + (size_t)refl(b + 3) * 256 + (lane << 2));
        const int m = b - 1, r = b - 2;
        const bool doM = (b + 2 >= mlo) && (b + 2 <= mlo + 15);
        float4 ocg;
        if (doM) ocg = *(const float4*)(oimg + (size_t)(b + 2) * 256 + (lane << 2));
        float hb[4];
        HB(cur, hb);
        float t[4], u[4], blv[4];
        #pragma unroll
        for (int k = 0; k < 4; ++k) {
            blv[k] = W0*(hwB[k] + hb[k]) + W1*(hwC[k] + hwE[k]) + W2*hwD[k];
            float lo = (m == 0)   ? boQ[k] : boP[k];
            float hi = (m == 255) ? boQ[k] : blv[k];
            t[k] = lo + 2.f*boQ[k] + hi;
            u[k] = hi - lo;
        }
        float Lt = dpp_shr1(t[3], t[0]), Rt = dpp_shl1(t[0], t[3]);
        float Lu = dpp_shr1(u[3], u[0]), Ru = dpp_shl1(u[0], u[3]);
        float gx[4], gy[4], mgC[4];
        gx[0] = t[1] - Lt; gx[1] = t[2] - t[0]; gx[2] = t[3] - t[1]; gx[3] = Rt - t[2];
        gy[0] = (Lu + u[1]) + 2.f*u[0];  gy[1] = (u[0] + u[2]) + 2.f*u[1];
        gy[2] = (u[1] + u[3]) + 2.f*u[2]; gy[3] = (u[2] + Ru) + 2.f*u[3];
        #pragma unroll
        for (int k = 0; k < 4; ++k) mgC[k] = fmaf(gx[k], gx[k], fmaf(gy[k], gy[k], 1e-6f));
        if (m < 0 || m > 255) { mgC[0]=mgC[1]=mgC[2]=mgC[3]=0.f; }
        float CL = dpp_shr1z(mgC[3]), CR = dpp_shl1z(mgC[0]);
        if (r >= R0 && r <= R1) donms(mgC, CL, CR, mout + r * 8);
        if (doM) MSE4(cur, ocg);
        #pragma unroll
        for (int k = 0; k < 4; ++k) {
            hwB[k]=hwC[k]; hwC[k]=hwD[k]; hwD[k]=hwE[k]; hwE[k]=hb[k];
            boP[k]=boQ[k]; boQ[k]=blv[k];
            mgA[k]=mgB[k]; mgB[k]=mgC[k];
            gxp[k]=gx[k];  gyp[k]=gy[k];
        }
        mgAL=mgBL; mgBL=CL; mgAR=mgBR; mgBR=CR;
        cur = nxt;
    };

    // branch-free interior row step, 2-deep prefetch on both streams
    auto fastrow = [&](const int b) {
        float4 nxt = *pi; pi += 64;                       // img row b+4
        const bool doM2 = ((unsigned)(b + 4 - mloF) <= spanF);
        float4 oc2;
        if (doM2) oc2 = *po;                              // oimg row b+4 (in-image when gated)
        po += 64;
        float hb[4];
        HB(cur, hb);
        float blv[4];
        #pragma unroll
        for (int k = 0; k < 4; ++k)
            blv[k] = W0*(hwB[k] + hb[k]) + W1*(hwC[k] + hwE[k]) + W2*hwD[k];
        float gx[4], gy[4], mgC[4], CL, CR;
        SOB(boP, boQ, blv, gx, gy, mgC, CL, CR);
        donms(mgC, CL, CR, mo); mo += 8;
        const bool doMc = ((unsigned)(b + 2 - mloF) <= spanF);
        if (doMc) MSE4(cur, oc);                          // oc loaded 2 rows ago
        #pragma unroll
        for (int k = 0; k < 4; ++k) {
            hwB[k]=hwC[k]; hwC[k]=hwD[k]; hwD[k]=hwE[k]; hwE[k]=hb[k];
            boP[k]=boQ[k]; boQ[k]=blv[k];
            mgA[k]=mgB[k]; mgB[k]=mgC[k];
            gxp[k]=gx[k];  gyp[k]=gy[k];
        }
        mgAL=mgBL; mgBL=CL; mgAR=mgBR; mgBR=CR;
        cur = nx1; nx1 = nxt;
        oc = oc1; oc1 = oc2;
    };

    int b;
    if (band == 0) {
        // generic prologue: reflect rows + m==0 guard. Steps b=-6..1 (8), no NMS emitted.
        #pragma unroll
        for (int k = 0; k < 4; ++k) {
            hwB[k]=hwC[k]=hwD[k]=hwE[k]=0.f; boP[k]=boQ[k]=0.f;
            mgA[k]=mgB[k]=0.f; gxp[k]=gyp[k]=0.f;
        }
        mgAL=mgAR=mgBL=mgBR=0.f;
        b = -6;
        cur = *(const float4*)(img + (size_t)refl(b + 2) * 256 + (lane << 2));
        for (; b <= 1; ++b) steprow(b);                  // ends with cur = row 4, b = 2
        nx1 = *((const float4*)(img + (size_t)5 * 256) + lane);
        pi = (const float4*)img + ((size_t)6 << 6) + lane;
    } else {
        // straight-line minimal warm-up (all rows direct; no guards for bands 1-7)
        auto ldr = [&](int r){ return *((const float4*)(img  + (size_t)r * 256) + lane); };
        auto ldo = [&](int r){ return *((const float4*)(oimg + (size_t)r * 256) + lane); };
        float4 c0 = ldr(R0 - 4), c1 = ldr(R0 - 3);
        float h0[4],h1[4],h2[4],h3[4],h4[4],h5[4],h6[4],h7[4];
        float bo0[4],bo1[4],bo2[4],bo3[4];
        HB(c0, h0); c0 = ldr(R0 - 2);
        HB(c1, h1); c1 = ldr(R0 - 1);
        HB(c0, h2); c0 = ldr(R0);
        HB(c1, h3); c1 = ldr(R0 + 1);
        if (isPred) { float4 o = ldo(R0);     MSE4(c0, o); }
        HB(c0, h4); c0 = ldr(R0 + 2);
        if (isPred) { float4 o = ldo(R0 + 1); MSE4(c1, o); }
        HB(c1, h5); c1 = ldr(R0 + 3);
        VB(h0, h1, h2, h3, h4, bo0);                     // blv row R0-2
        VB(h1, h2, h3, h4, h5, bo1);                     // blv row R0-1
        if (isPred) { float4 o = ldo(R0 + 2); MSE4(c0, o); }
        HB(c0, h6); c0 = ldr(R0 + 4);
        VB(h2, h3, h4, h5, h6, bo2);                     // blv row R0
        { float dgx[4], dgy[4]; SOB(bo0, bo1, bo2, dgx, dgy, mgA, mgAL, mgAR); }  // mg row R0-1
        if (isPred) { float4 o = ldo(R0 + 3); MSE4(c1, o); }
        HB(c1, h7);
        VB(h3, h4, h5, h6, h7, bo3);                     // blv row R0+1
        SOB(bo1, bo2, bo3, gxp, gyp, mgB, mgBL, mgBR);   // sobel/mag row R0
        #pragma unroll
        for (int k = 0; k < 4; ++k) {
            hwB[k]=h4[k]; hwC[k]=h5[k]; hwD[k]=h6[k]; hwE[k]=h7[k];
            boP[k]=bo2[k]; boQ[k]=bo3[k];
        }
        cur = c0;                                        // row R0+4
        nx1 = ldr(R0 + 5);                               // row R0+5
        pi = (const float4*)img + ((size_t)(R0 + 6) << 6) + lane;
        b = R0 + 2;
    }
    po = (const float4*)oimg + ((size_t)(R0 + 6) << 6) + lane;
    if (isPred) {                                        // prime MSE stream (rows R0+4, R0+5)
        oc  = *((const float4*)(oimg + (size_t)(R0 + 4) * 256) + lane);
        oc1 = *((const float4*)(oimg + (size_t)(R0 + 5) * 256) + lane);
    }
    mo = mout + (size_t)R0 * 8;

    const int quads = (band == 7) ? 6 : 8;               // fast NMS rows R0..(R0+31 | R0+23)
    for (int q = 0; q < quads; ++q) {
        fastrow(b); fastrow(b + 1); fastrow(b + 2); fastrow(b + 3); b += 4;
    }
    if (band == 7) {
        for (; b <= 257; ++b) steprow(b);                // rows 248..255: m==255 + refl tail
    }

    for (int off = 32; off; off >>= 1) acc += __shfl_down(acc, off);
    if (lane == 0)
        atomicAdd(&sse[(blockIdx.y * 2 + blockIdx.x) & 63], (double)acc);
}

// ------- Kernel 2: per-pair hysteresis fixpoint + inline strong-diff count ----------
// Row layout: 8 u64 per row = [w0..w3, s0..s3]. Bit: word j bit l = col 4l+j.
__global__ __launch_bounds__(256) void k_hyst(const u64* __restrict__ masks,
                                              u64* __restrict__ cnt)
{
    const int pr = blockIdx.x;                       // pair 0..191
    const u64* rp = masks + (size_t)pr * 2048 + (size_t)threadIdx.x * 8;
    const u64* rt = masks + (size_t)(pr + NIMG) * 2048 + (size_t)threadIdx.x * 8;
    const int r = threadIdx.x;                       // row 0..255
    __shared__ u64 hd[8][256];
    __shared__ int flg[2];
    __shared__ int wsum[4];
    ulonglong2 a0 = ((const ulonglong2*)rp)[0];
    ulonglong2 a1 = ((const ulonglong2*)rp)[1];
    ulonglong2 a2 = ((const ulonglong2*)rp)[2];
    ulonglong2 a3 = ((const ulonglong2*)rp)[3];
    ulonglong2 b0 = ((const ulonglong2*)rt)[0];
    ulonglong2 b1 = ((const ulonglong2*)rt)[1];
    ulonglong2 b2 = ((const ulonglong2*)rt)[2];
    ulonglong2 b3 = ((const ulonglong2*)rt)[3];
    u64 pw0=a0.x, pw1=a0.y, pw2=a1.x, pw3=a1.y;
    u64 ps0=a2.x, ps1=a2.y, ps2=a3.x, ps3=a3.y;
    u64 tw0=b0.x, tw1=b0.y, tw2=b1.x, tw3=b1.y;
    u64 ts0=b2.x, ts1=b2.y, ts2=b3.x, ts3=b3.y;
    if (r < 2) flg[r] = 0;
    const int up = r ? r - 1 : 0, dn = (r < 255) ? r + 1 : 255;
    for (int k = 0;; ++k) {
        u64 hp0 = ps0 | (ps3 << 1) | ps1;
        u64 hp1 = ps1 | ps0 | ps2;
        u64 hp2 = ps2 | ps1 | ps3;
        u64 hp3 = ps3 | ps2 | (ps0 >> 1);
        u64 ht0 = ts0 | (ts3 << 1) | ts1;
        u64 ht1 = ts1 | ts0 | ts2;
        u64 ht2 = ts2 | ts1 | ts3;
        u64 ht3 = ts3 | ts2 | (ts0 >> 1);
        hd[0][r]=hp0; hd[1][r]=hp1; hd[2][r]=hp2; hd[3][r]=hp3;
        hd[4][r]=ht0; hd[5][r]=ht1; hd[6][r]=ht2; hd[7][r]=ht3;
        if (r == 0) flg[(k + 1) & 1] = 0;
        __syncthreads();
        u64 n0 = ps0 | ((hp0 | hd[0][up] | hd[0][dn]) & pw0);
        u64 n1 = ps1 | ((hp1 | hd[1][up] | hd[1][dn]) & pw1);
        u64 n2 = ps2 | ((hp2 | hd[2][up] | hd[2][dn]) & pw2);
        u64 n3 = ps3 | ((hp3 | hd[3][up] | hd[3][dn]) & pw3);
        u64 m0 = ts0 | ((ht0 | hd[4][up] | hd[4][dn]) & tw0);
        u64 m1 = ts1 | ((ht1 | hd[5][up] | hd[5][dn]) & tw1);
        u64 m2 = ts2 | ((ht2 | hd[6][up] | hd[6][dn]) & tw2);
        u64 m3 = ts3 | ((ht3 | hd[7][up] | hd[7][dn]) & tw3);
        u64 chg = (n0^ps0)|(n1^ps1)|(n2^ps2)|(n3^ps3)|(m0^ts0)|(m1^ts1)|(m2^ts2)|(m3^ts3);
        ps0=n0; ps1=n1; ps2=n2; ps3=n3; ts0=m0; ts1=m1; ts2=m2; ts3=m3;
        if (chg) flg[k & 1] = 1;
        __syncthreads();
        if (!flg[k & 1]) break;
    }
    int c = __popcll(ps0^ts0) + __popcll(ps1^ts1) + __popcll(ps2^ts2) + __popcll(ps3^ts3);
    for (int off = 32; off; off >>= 1) c += __shfl_down(c, off);
    if ((threadIdx.x & 63) == 0) wsum[threadIdx.x >> 6] = c;
    __syncthreads();
    if (threadIdx.x == 0)
        atomicAdd(cnt, (u64)(wsum[0] + wsum[1] + wsum[2] + wsum[3]));
}

// ---------------- Kernel 3: combine --------------------------------------------------
__global__ void k_final(const double* __restrict__ sse, const u64* __restrict__ cnt,
                        float* __restrict__ out)
{
    double s = 0.0;
    for (int i = 0; i < 64; ++i) s += sse[i];
    float mse1 = (float)(s / (double)N_TOTAL);
    float mse2 = (float)((double)(*cnt) / (double)N_TOTAL);
    out[0] = 0.85f * mse1 + (1.0f - 0.85f) * mse2;
}

extern "C" void kernel_launch(void* const* d_in, const int* in_sizes, int n_in,
                              void* d_out, int out_size, void* d_ws, size_t ws_size,
                              hipStream_t stream)
{
    const float* pred  = (const float*)d_in[0];
    const float* batch = (const float*)d_in[1];
    float* out = (float*)d_out;
    double* sse = (double*)d_ws;                       // 64 doubles
    u64* cnt    = (u64*)((char*)d_ws + 512);
    u64* masks  = (u64*)((char*)d_ws + 1024);          // 384 * 2048 u64

    hipMemsetAsync(d_ws, 0, 1024, stream);
    dim3 g1(2, 384);                                   // 8 bands x 384 images
    k_edges<<<g1, 256, 0, stream>>>(pred, batch, masks, sse);
    k_hyst<<<192, 256, 0, stream>>>(masks, cnt);
    k_final<<<1, 1, 0, stream>>>(sse, cnt, out);
}